// Round 2
// 394.368 us; speedup vs baseline: 1.0167x; 1.0167x over previous
//
#include <hip/hip_runtime.h>

#define N_   32
#define C_   512
#define H_   56
#define W_   56
#define S_   16    // NUM_SPLIT
#define CP_  32    // channels per split
#define HW_  (H_*W_)              // 3136
#define TOT_ ((size_t)N_*C_*HW_)  // 51380224

typedef float f32x4 __attribute__((ext_vector_type(4)));  // native vec for nontemporal builtin

__constant__ int d_mx[16] = {0,0,6,0,0,1,1,4,5,1,3,0,0,0,3,2};
__constant__ int d_my[16] = {0,1,0,5,2,0,2,0,0,6,0,4,6,3,5,2};

// ---------------- Kernel 1: adaptive avg pool 56x56 -> 7x7 -------------------
// One plane per 256-thread block. Fully-coalesced float4 global reads staged
// through LDS, then 8x8 block sums from LDS (196 threads, quarter-block each).
// NOTE: reads are TEMPORAL on purpose — they warm the 256 MB Infinity Cache
// with x so scale_kernel's re-read hits L3 instead of HBM.
__global__ void __launch_bounds__(256) pool_kernel(const float* __restrict__ x,
                                                   float* __restrict__ xp) {
    __shared__ float tile[HW_];       // 12.5 KB
    __shared__ float part[49 * 4];
    int plane = blockIdx.x;           // n*C_ + c
    int t = threadIdx.x;
    const float4* src = reinterpret_cast<const float4*>(x + (size_t)plane * HW_);
    for (int i = t; i < HW_ / 4; i += 256)            // 784 float4, coalesced
        *reinterpret_cast<float4*>(&tile[i * 4]) = src[i];
    __syncthreads();
    if (t < 196) {
        int bin = t >> 2, q = t & 3;                  // quarter-block = 2 rows x 8 cols
        int oi = bin / 7, oj = bin % 7;
        const float* rp = &tile[(oi * 8 + q * 2) * W_ + oj * 8];
        float s = 0.f;
#pragma unroll
        for (int rr = 0; rr < 2; ++rr)
#pragma unroll
            for (int cc = 0; cc < 8; ++cc) s += rp[rr * W_ + cc];
        part[t] = s;
    }
    __syncthreads();
    if (t < 49) {
        float s = part[t * 4] + part[t * 4 + 1] + part[t * 4 + 2] + part[t * 4 + 3];
        xp[(size_t)plane * 49 + t] = s * (1.0f / 64.0f);
    }
}

// ---------------- Kernel 2: head (convs + DCT blend + MLP) -> cw -------------
// One 256-thread block per sample. ALL of xp[n] (512ch x 49 = 98 KB) staged
// into LDS in one coalesced float4 pass (gfx950 allows >64 KB static LDS).
// Every later phase is LDS/register-fed; single load, fewer barriers than the
// previous two-chunk version.
__global__ void __launch_bounds__(256) head_kernel(
        const float* __restrict__ xp,
        const float* __restrict__ c1w, const float* __restrict__ c1b,
        const float* __restrict__ c2w, const float* __restrict__ c2b,
        const float* __restrict__ w1,  const float* __restrict__ w2,
        float* __restrict__ cwout) {
    __shared__ float tile[C_ * 49];   // 25088 floats = 98 KB (full sample)
    __shared__ float sD[7][7];
    __shared__ float a1[S_ * 9];
    __shared__ float wcomb[S_ * 49];
    __shared__ float svec[C_];
    __shared__ float hpart[256];
    __shared__ float hmid[32];
    __shared__ float sfrac[S_];
    __shared__ int   sleft[S_];

    int n = blockIdx.x, t = threadIdx.x;
    const float4* src = reinterpret_cast<const float4*>(xp + (size_t)n * C_ * 49);
    for (int i = t; i < C_ * 49 / 4; i += 256)       // 6272 float4, coalesced
        *reinterpret_cast<float4*>(&tile[i * 4]) = src[i];

    if (t < 49) {
        int f = t / 7, p = t % 7;
        float v = cosf(3.14159265358979323846f * f * (p + 0.5f) / 7.0f) * 0.3779644730092272f;
        if (f >= 1) v *= 1.4142135623730951f;
        sD[f][p] = v;
    }
    __syncthreads();

    // -------- conv1: 16 splits x 9 outputs, all from LDS ---------------------
    if (t < S_ * 9) {
        int s = t / 9, o = t - s * 9, oi = o / 3, oj = o - oi * 3;
        float acc = c1b[s];
        const float* xb = &tile[s * CP_ * 49];
        const float* wb = c1w + s * CP_ * 9;
        for (int ic = 0; ic < CP_; ++ic) {
#pragma unroll
            for (int ki = 0; ki < 3; ++ki)
#pragma unroll
                for (int kj = 0; kj < 3; ++kj)
                    acc += xb[ic * 49 + (oi * 2 + ki) * 7 + (oj * 2 + kj)]
                         * wb[ic * 9 + ki * 3 + kj];
        }
        a1[t] = fminf(fmaxf(acc + 3.f, 0.f), 6.f) * (1.f / 6.f);
    }
    __syncthreads();

    // -------- conv2 (depthwise 3x3 on 3x3 -> 1), pred ------------------------
    if (t < S_) {
        float acc = c2b[t];
#pragma unroll
        for (int k = 0; k < 9; ++k) acc += a1[t * 9 + k] * c2w[t * 9 + k];
        float pred = fminf(fmaxf(acc * 16.f, 0.f), 14.9f);
        int l = (int)pred;
        sleft[t] = l;
        sfrac[t] = pred - (float)l;
    }
    __syncthreads();

    // -------- combined DCT filter per split ----------------------------------
    for (int i = t; i < S_ * 49; i += 256) {
        int s = i / 49, p = i - s * 49, hh = p / 7, ww = p - hh * 7;
        int l = sleft[s], r = l + 1;
        float fr = sfrac[s];
        wcomb[i] = (1.f - fr) * sD[d_mx[l]][hh] * sD[d_my[l]][ww]
                 +        fr  * sD[d_mx[r]][hh] * sD[d_my[r]][ww];
    }
    __syncthreads();

    // -------- svec: per-channel 49-dot, fully LDS-fed ------------------------
    for (int ch = t; ch < C_; ch += 256) {
        const float* xb = &tile[ch * 49];
        const float* wb = &wcomb[(ch >> 5) * 49];
        float acc = 0.f;
#pragma unroll
        for (int p = 0; p < 49; ++p) acc += xb[p] * wb[p];
        svec[ch] = acc;
    }
    __syncthreads();

    // -------- hmid = hard_sigmoid(svec @ w1.T), parallel over 256 threads ----
    {
        int o = t >> 3, g = t & 7;     // 32 outputs x 8 chunks of 64
        const float4* wv = reinterpret_cast<const float4*>(w1 + o * C_ + g * 64);
        const float4* sv = reinterpret_cast<const float4*>(&svec[g * 64]);
        float acc = 0.f;
#pragma unroll
        for (int j = 0; j < 16; ++j) {
            float4 a = sv[j], b = wv[j];
            acc += a.x * b.x + a.y * b.y + a.z * b.z + a.w * b.w;
        }
        hpart[t] = acc;
    }
    __syncthreads();
    if (t < 32) {
        float acc = 0.f;
#pragma unroll
        for (int g = 0; g < 8; ++g) acc += hpart[t * 8 + g];
        hmid[t] = fminf(fmaxf(acc + 3.f, 0.f), 6.f) * (1.f / 6.f);
    }
    __syncthreads();

    // -------- cw = sigmoid(hmid @ w2.T) --------------------------------------
    for (int ch = t; ch < C_; ch += 256) {
        const float4* wr = reinterpret_cast<const float4*>(w2 + ch * 32);
        float acc = 0.f;
#pragma unroll
        for (int j = 0; j < 8; ++j) {
            float4 b = wr[j];
            const float4 h = reinterpret_cast<const float4*>(hmid)[j];
            acc += h.x * b.x + h.y * b.y + h.z * b.z + h.w * b.w;
        }
        cwout[n * C_ + ch] = 1.f / (1.f + expf(-acc));
    }
}

// ---------------- Kernel 3: out = x * cw[n,c] --------------------------------
// One plane per block: cw load becomes a single uniform (scalar) load, no
// integer division. Stores are NONTEMPORAL (nt bit) so the 196 MB of out does
// not write-allocate into L3 and evict the pool-warmed x mid-pass — the x
// re-read should then be served largely from Infinity Cache.
__global__ void __launch_bounds__(256) scale_kernel(const float* __restrict__ x,
                                                    const float* __restrict__ cw,
                                                    float* __restrict__ out) {
    int plane = blockIdx.x;
    int t = threadIdx.x;
    float wsc = cw[plane];
    const f32x4* src = reinterpret_cast<const f32x4*>(x + (size_t)plane * HW_);
    f32x4* dst = reinterpret_cast<f32x4*>(out + (size_t)plane * HW_);

    // 784 float4 per plane = 3 full rounds + 16-thread tail. Issue all loads
    // up-front for memory-level parallelism, then scale+store.
    f32x4 u0 = src[t];
    f32x4 u1 = src[t + 256];
    f32x4 u2 = src[t + 512];
    f32x4 u3;
    if (t < 16) u3 = src[t + 768];

    u0 *= wsc;
    u1 *= wsc;
    u2 *= wsc;

    __builtin_nontemporal_store(u0, dst + t);
    __builtin_nontemporal_store(u1, dst + t + 256);
    __builtin_nontemporal_store(u2, dst + t + 512);
    if (t < 16) {
        u3 *= wsc;
        __builtin_nontemporal_store(u3, dst + t + 768);
    }
}

extern "C" void kernel_launch(void* const* d_in, const int* in_sizes, int n_in,
                              void* d_out, int out_size, void* d_ws, size_t ws_size,
                              hipStream_t stream) {
    const float* x   = (const float*)d_in[0];
    const float* c1w = (const float*)d_in[1];
    const float* c1b = (const float*)d_in[2];
    const float* c2w = (const float*)d_in[3];
    const float* c2b = (const float*)d_in[4];
    const float* w1  = (const float*)d_in[5];
    const float* w2  = (const float*)d_in[6];
    float* out = (float*)d_out;

    float* xp    = (float*)d_ws;                 // N*C*49 fp32 = 3.2 MB
    float* cwbuf = xp + (size_t)N_ * C_ * 49;    // N*C fp32

    pool_kernel<<<N_ * C_, 256, 0, stream>>>(x, xp);
    head_kernel<<<N_, 256, 0, stream>>>(xp, c1w, c1b, c2w, c2b, w1, w2, cwbuf);
    scale_kernel<<<N_ * C_, 256, 0, stream>>>(x, cwbuf, out);
}